// Round 12
// baseline (7541.927 us; speedup 1.0000x reference)
//
#include <hip/hip_runtime.h>

#define NS 4096   // sentences
#define DI 1024   // D_IN
#define HH 1024   // HID
#define NB 256    // persistent blocks
#define TPB 1024  // 16 waves/block
#define LOG2E 1.4426950408889634f

// barrier layout (ints): arrival slot for block b at b*32 (128B apart)
#define BAR_INTS (NB*32)

// keep a loaded value alive in VGPRs (not rematerializable)
#define PINU2(v) asm volatile("" : "+v"((v).x), "+v"((v).y))

__device__ __forceinline__ float ld_b(const float* p){
  return __hip_atomic_load(p, __ATOMIC_RELAXED, __HIP_MEMORY_SCOPE_AGENT);
}
__device__ __forceinline__ int ld_i(const int* p){
  return __hip_atomic_load(p, __ATOMIC_RELAXED, __HIP_MEMORY_SCOPE_AGENT);
}
__device__ __forceinline__ void st_b(float* p, float v){
  __hip_atomic_store(p, v, __ATOMIC_RELAXED, __HIP_MEMORY_SCOPE_AGENT);
}
__device__ __forceinline__ void st_i(int* p, int v){
  __hip_atomic_store(p, v, __ATOMIC_RELAXED, __HIP_MEMORY_SCOPE_AGENT);
}
__device__ __forceinline__ float fexp2f_(float x){ return __builtin_amdgcn_exp2f(x); }
__device__ __forceinline__ float frcpf_(float x){ return __builtin_amdgcn_rcpf(x); }
__device__ __forceinline__ float ftanh_(float x){ float t=fexp2f_(x*(2.f*LOG2E)); return 1.f-2.f*frcpf_(t+1.f); }
__device__ __forceinline__ float fsigm_(float x){ return frcpf_(1.f+fexp2f_(-x*LOG2E)); }
__device__ __forceinline__ float fexpf_(float x){ return fexp2f_(x*LOG2E); }
__device__ __forceinline__ float bl(unsigned u){ return __uint_as_float(u<<16); }
__device__ __forceinline__ float bh(unsigned u){ return __uint_as_float(u & 0xffff0000u); }
__device__ __forceinline__ unsigned short rne(float f){
  unsigned u = __float_as_uint(f);
  u += 0x7FFFu + ((u>>16)&1u);
  return (unsigned short)(u>>16);
}
__device__ __forceinline__ float red64(float v){
  #pragma unroll
  for (int off=32; off; off>>=1) v += __shfl_xor(v, off, 64);
  return v;
}
// dot of 4 packed bf16 (uint2) with float4
__device__ __forceinline__ float dot4u(uint2 u, float4 x){
  float s = bl(u.x)*x.x;
  s = fmaf(bh(u.x), x.y, s);
  s = fmaf(bl(u.y), x.z, s);
  s = fmaf(bh(u.y), x.w, s);
  return s;
}
__device__ __forceinline__ float att4u(uint2 u, float4 q, float4 v){
  float s = ftanh_(bl(u.x)+q.x)*v.x;
  s = fmaf(ftanh_(bh(u.x)+q.y), v.y, s);
  s = fmaf(ftanh_(bl(u.y)+q.z), v.z, s);
  s = fmaf(ftanh_(bh(u.y)+q.w), v.w, s);
  return s;
}

// ---- grid barrier v5: store-arrival + replicated sweep detection, NO release ----
// arrival: one agent store per block into its own 128B-padded slot (no RMWs).
// detect:  wave 0 of EVERY block sweeps all 256 slots (4/lane, __all on
//          lane-min) — r8's proven detector loop, replicated per block so the
//          release hop disappears. Read-only sharing of 256 hot LLC lines.
// skew:    monotonic slots + '>' compare; max skew is 1 phase (a block can't
//          pass barrier N+1 until all slots exceed ep+1).
__device__ __forceinline__ void gbar(int* bar, int ep){
  __syncthreads();                 // all waves' data stores drained (vmcnt 0)
  const int tid = threadIdx.x;
  if (tid == 0){
    asm volatile("s_waitcnt vmcnt(0) lgkmcnt(0)" ::: "memory");
    st_i(bar + blockIdx.x*32, ep+1);
  }
  if (tid < 64){
    const int b0 = tid*4;
    for(;;){
      int m0 = ld_i(bar + (b0+0)*32);
      int m1 = ld_i(bar + (b0+1)*32);
      int m2 = ld_i(bar + (b0+2)*32);
      int m3 = ld_i(bar + (b0+3)*32);
      int mn = min(min(m0,m1),min(m2,m3));
      if (__all(mn > ep)) break;
      __builtin_amdgcn_s_sleep(1);
    }
  }
  __syncthreads();
}

// ---------------- precompute kernels ----------------
__global__ void initk(int* bar){ bar[blockIdx.x*1024 + threadIdx.x] = 0; }  // <<<8,1024>>>

template<int MODE>  // 0: fp32 C; 1: bf16 CH; 2: bf16 CH^T; 3: fp32 C + bf16 CH
__global__ __launch_bounds__(256) void gemmk(const float* __restrict__ A,
                                             const float* __restrict__ B,
                                             float* __restrict__ C,
                                             unsigned short* __restrict__ CH,
                                             int M, int N, int K)
{
  __shared__ float As[64][17];
  __shared__ float Bs[16][68];
  const int tid = threadIdx.x;
  const int tx = tid & 15, ty = tid >> 4;
  const int r0 = blockIdx.y*64, c0 = blockIdx.x*64;
  float acc[4][4] = {};
  for (int k0 = 0; k0 < K; k0 += 16){
    int ar = tid >> 2, aq = tid & 3;
    float4 a4 = *(const float4*)&A[(size_t)(r0+ar)*K + k0 + aq*4];
    As[ar][aq*4+0]=a4.x; As[ar][aq*4+1]=a4.y; As[ar][aq*4+2]=a4.z; As[ar][aq*4+3]=a4.w;
    int br = tid >> 4, bq = tid & 15;
    float4 b4 = *(const float4*)&B[(size_t)(k0+br)*N + c0 + bq*4];
    Bs[br][bq*4+0]=b4.x; Bs[br][bq*4+1]=b4.y; Bs[br][bq*4+2]=b4.z; Bs[br][bq*4+3]=b4.w;
    __syncthreads();
    #pragma unroll
    for (int kk=0; kk<16; ++kk){
      float a0=As[ty*4+0][kk], a1=As[ty*4+1][kk], a2=As[ty*4+2][kk], a3=As[ty*4+3][kk];
      float b0=Bs[kk][tx*4+0], b1=Bs[kk][tx*4+1], b2=Bs[kk][tx*4+2], b3=Bs[kk][tx*4+3];
      acc[0][0]+=a0*b0; acc[0][1]+=a0*b1; acc[0][2]+=a0*b2; acc[0][3]+=a0*b3;
      acc[1][0]+=a1*b0; acc[1][1]+=a1*b1; acc[1][2]+=a1*b2; acc[1][3]+=a1*b3;
      acc[2][0]+=a2*b0; acc[2][1]+=a2*b1; acc[2][2]+=a2*b2; acc[2][3]+=a2*b3;
      acc[3][0]+=a3*b0; acc[3][1]+=a3*b1; acc[3][2]+=a3*b2; acc[3][3]+=a3*b3;
    }
    __syncthreads();
  }
  if constexpr (MODE==0 || MODE==3){
    #pragma unroll
    for (int i=0;i<4;++i){
      float4 o; o.x=acc[i][0]; o.y=acc[i][1]; o.z=acc[i][2]; o.w=acc[i][3];
      *(float4*)&C[(size_t)(r0+ty*4+i)*N + c0 + tx*4] = o;
    }
  }
  if constexpr (MODE==1 || MODE==3){
    #pragma unroll
    for (int i=0;i<4;++i){
      ushort4 o; o.x=rne(acc[i][0]); o.y=rne(acc[i][1]); o.z=rne(acc[i][2]); o.w=rne(acc[i][3]);
      *(ushort4*)&CH[(size_t)(r0+ty*4+i)*N + c0 + tx*4] = o;
    }
  }
  if constexpr (MODE==2){
    __shared__ float Cs[64][65];
    #pragma unroll
    for (int i=0;i<4;++i)
      #pragma unroll
      for (int j=0;j<4;++j) Cs[ty*4+i][tx*4+j] = acc[i][j];
    __syncthreads();
    #pragma unroll
    for (int e=0;e<16;++e){
      int idx = tid + 256*e;
      int cc = idx >> 6, rr = idx & 63;
      CH[(size_t)(c0+cc)*M + r0 + rr] = rne(Cs[rr][cc]);
    }
  }
}

__global__ void transpkH(const float* __restrict__ in, unsigned short* __restrict__ out, int R, int C){
  __shared__ float s[32][33];
  int c0 = blockIdx.x*32, r0 = blockIdx.y*32;
  int x = threadIdx.x, y = threadIdx.y;
  for (int i=0;i<32;i+=8) s[y+i][x] = in[(size_t)(r0+y+i)*C + c0 + x];
  __syncthreads();
  for (int i=0;i<32;i+=8) out[(size_t)(c0+y+i)*R + r0 + x] = rne(s[x][y+i]);
}

__global__ void convk(const float* __restrict__ in, unsigned short* __restrict__ out, int n){
  int i = (blockIdx.x*blockDim.x + threadIdx.x)*4;
  if (i < n){
    float4 f = *(const float4*)&in[i];
    ushort4 o; o.x=rne(f.x); o.y=rne(f.y); o.z=rne(f.z); o.w=rne(f.w);
    *(ushort4*)&out[i] = o;
  }
}

// ---------------- persistent step kernel (r6/r11 body, v5 barrier) ----------------
__global__ __launch_bounds__(TPB) void stepk(
  const unsigned short* __restrict__ attn_featH, const unsigned short* __restrict__ hop_featH,
  const unsigned short* __restrict__ HQTH, const unsigned short* __restrict__ HATH,
  const unsigned short* __restrict__ memTH, const unsigned short* __restrict__ wqTH,
  const unsigned short* __restrict__ wihH, const unsigned short* __restrict__ whhH,
  const float* __restrict__ b_ih, const float* __restrict__ b_hh,
  const float* __restrict__ hop_v, const float* __restrict__ attn_v,
  const float* __restrict__ init_h, const float* __restrict__ init_c,
  const float* __restrict__ init_i,
  const float* __restrict__ score_w, const float* __restrict__ score_b,
  const int* __restrict__ n_step,
  float* xst, float* hb, float* qwb, float* wb, int* bar,
  float* __restrict__ out)
{
  const int bb = blockIdx.x, tid = threadIdx.x;
  const int wv = tid>>6, ln = tid&63;
  const int g = wv>>2, sub = wv&3;
  const int rowA = 16*bb + wv;            // att row
  const int R    = g*HH + 4*bb + sub;     // LSTM gate row

  __shared__ unsigned short mls[3][4][4096];  // 96KB: HQ/HA/memT rows for this block's 4 cols
  __shared__ float xh[2*HH];
  __shared__ float qls[HH];
  __shared__ float wls[NS];
  __shared__ float vhop[HH], vatt[HH], swls[HH];
  __shared__ float gbuf[16], pbuf[16], sbuf[16], cl[4];
  int ep = 0;

  // ---- stage col matrices in LDS (once) ----
  #pragma unroll
  for (int gg2=0; gg2<4; ++gg2){
    const size_t r = (size_t)(4*bb+gg2)*NS + tid*4;
    *(ushort4*)&mls[0][gg2][tid*4] = *(const ushort4*)&HQTH [r];
    *(ushort4*)&mls[1][gg2][tid*4] = *(const ushort4*)&HATH [r];
    *(ushort4*)&mls[2][gg2][tid*4] = *(const ushort4*)&memTH[r];
  }

  // ---- pin remaining rows in registers (33 dwords / lane) ----
  uint2 hopf[4], attnf[4], wihr[4], whhr[4], wqr;
  #pragma unroll
  for (int ps=0; ps<4; ++ps){
    const int e0 = ps*256 + ln*4;
    hopf[ps]  = *(const uint2*)&hop_featH [(size_t)rowA*HH + e0];  PINU2(hopf[ps]);
    attnf[ps] = *(const uint2*)&attn_featH[(size_t)rowA*HH + e0];  PINU2(attnf[ps]);
    wihr[ps]  = *(const uint2*)&wihH[(size_t)R*DI + e0];           PINU2(wihr[ps]);
    whhr[ps]  = *(const uint2*)&whhH[(size_t)R*HH + e0];           PINU2(whhr[ps]);
  }
  wqr = *(const uint2*)&wqTH[(size_t)(4*bb+g)*HH + sub*256 + ln*4]; PINU2(wqr);
  const float bR = b_ih[R] + b_hh[R];

  vhop[tid] = hop_v[tid];
  vatt[tid] = attn_v[tid];
  swls[tid] = score_w[tid];
  const int T = *n_step;
  const float sb = score_b[0];
  __syncthreads();

  for (int t=0; t<T; ++t){
    const int hw = (t+1)&1;
    // ---- Ph1: LSTM gates + h update; score[t-1] on block 0 ----
    if (t==0){ xh[tid] = init_i[tid]; xh[HH+tid] = init_h[tid]; }
    else     { xh[tid] = ld_b(&xst[tid]); xh[HH+tid] = ld_b(&hb[(t&1)*HH + tid]); }
    __syncthreads();
    {
      float p = 0.f;
      #pragma unroll
      for (int ps=0; ps<4; ++ps){
        const int e0 = ps*256 + ln*4;
        p += dot4u(wihr[ps], *(const float4*)&xh[e0]);
        p += dot4u(whhr[ps], *(const float4*)&xh[HH+e0]);
      }
      p = red64(p);
      if (ln==0) gbuf[wv] = p + bR;
    }
    __syncthreads();
    if (bb==0 && wv==0 && t>0){
      float a = 0.f;
      #pragma unroll
      for (int ps=0; ps<4; ++ps){
        const int e0 = ps*256 + ln*4;
        float4 x = *(const float4*)&xh[e0], s = *(const float4*)&swls[e0];
        a += x.x*s.x; a = fmaf(x.y,s.y,a); a = fmaf(x.z,s.z,a); a = fmaf(x.w,s.w,a);
      }
      a = red64(a);
      if (ln==0) out[t-1] = a + sb;
    }
    if (tid < 4){
      float ii=fsigm_(gbuf[tid]),   ff=fsigm_(gbuf[4+tid]);
      float gg=ftanh_(gbuf[8+tid]), oo=fsigm_(gbuf[12+tid]);
      float c = (t==0) ? init_c[4*bb+tid] : cl[tid];
      float c2 = ff*c + ii*gg;
      cl[tid] = c2;
      st_b(&hb[(size_t)hw*HH + 4*bb + tid], oo*ftanh_(c2));
    }
    gbar(bar, ep); ++ep;

    // ---- Ph2: qw1 = h @ hop_wq ----
    qls[tid] = ld_b(&hb[(size_t)hw*HH + tid]);
    __syncthreads();
    {
      float a = dot4u(wqr, *(const float4*)&qls[sub*256 + ln*4]);
      a = red64(a);
      if (ln==0) pbuf[wv] = a;
    }
    __syncthreads();
    if (tid < 4)
      st_b(&qwb[4*bb+tid], pbuf[4*tid]+pbuf[4*tid+1]+pbuf[4*tid+2]+pbuf[4*tid+3]);
    gbar(bar, ep); ++ep;

    // ---- 3 hops: att (own row, regs) | col (own 4 dims, LDS matrices) ----
    #pragma unroll
    for (int hop=0; hop<3; ++hop){
      // att: e = sum tanh(F[n]+qw).v -> w=exp(e)
      qls[tid] = ld_b(&qwb[tid]);
      __syncthreads();
      {
        float e = 0.f;
        #pragma unroll
        for (int ps=0; ps<4; ++ps){
          const int e0 = ps*256 + ln*4;
          float4 q = *(const float4*)&qls[e0];
          if (hop<2) e += att4u(hopf[ps],  q, *(const float4*)&vhop[e0]);
          else       e += att4u(attnf[ps], q, *(const float4*)&vatt[e0]);
        }
        e = red64(e);
        if (ln==0) st_b(&wb[rowA], fexpf_(e));   // |e|<=sum|v|: no overflow
      }
      gbar(bar, ep); ++ep;

      // col: stage all 4096 w in LDS; dot with LDS matrix rows; denom = LDS sum
      wls[tid]      = ld_b(&wb[tid]);
      wls[tid+1024] = ld_b(&wb[tid+1024]);
      wls[tid+2048] = ld_b(&wb[tid+2048]);
      wls[tid+3072] = ld_b(&wb[tid+3072]);
      __syncthreads();
      {
        float a = 0.f;
        const unsigned short* mrow = &mls[hop][g][sub*1024];
        #pragma unroll
        for (int ps=0; ps<4; ++ps){
          const int e0 = ps*256 + ln*4;
          float4 w4 = *(const float4*)&wls[sub*1024 + e0];
          uint2 m = *(const uint2*)&mrow[e0];
          a += dot4u(m, w4);
        }
        a = red64(a);
        if (ln==0) pbuf[wv] = a;
        // per-wave chunk sum of w for the softmax denominator (local)
        float4 sv = *(const float4*)&wls[wv*256 + ln*4];
        float s4 = sv.x + sv.y + sv.z + sv.w;
        s4 = red64(s4);
        if (ln==0) sbuf[wv] = s4;
      }
      __syncthreads();
      if (tid < 4){
        float stot = 0.f;
        #pragma unroll
        for (int k=0;k<16;++k) stot += sbuf[k];
        float s = (pbuf[4*tid]+pbuf[4*tid+1]+pbuf[4*tid+2]+pbuf[4*tid+3]) / stot;
        float* dst = (hop==2) ? xst : qwb;
        st_b(&dst[4*bb+tid], s);
      }
      gbar(bar, ep); ++ep;
    }
  }
  // final score for t = T-1
  if (bb==0 && wv==0 && T>0){
    float a = 0.f;
    #pragma unroll
    for (int m=0;m<16;++m){ int i = ln + (m<<6); a = fmaf(ld_b(&xst[i]), swls[i], a); }
    a = red64(a);
    if (ln==0) out[T-1] = a + sb;
  }
}

// ---------------- host launch ----------------
extern "C" void kernel_launch(void* const* d_in, const int* in_sizes, int n_in,
                              void* d_out, int out_size, void* d_ws, size_t ws_size,
                              hipStream_t stream)
{
  (void)in_sizes; (void)n_in; (void)out_size;
  const float* attn_mem = (const float*)d_in[0];
  const float* attn_wm  = (const float*)d_in[1];
  const float* attn_wq  = (const float*)d_in[2];
  const float* attn_v   = (const float*)d_in[3];
  const float* hop_wm   = (const float*)d_in[4];
  const float* hop_wq   = (const float*)d_in[5];
  const float* hop_v    = (const float*)d_in[6];
  const float* init_h   = (const float*)d_in[7];
  const float* init_c   = (const float*)d_in[8];
  const float* init_i   = (const float*)d_in[9];
  const float* w_ih     = (const float*)d_in[10];
  const float* w_hh     = (const float*)d_in[11];
  const float* b_ih     = (const float*)d_in[12];
  const float* b_hh     = (const float*)d_in[13];
  const float* score_w  = (const float*)d_in[14];
  const float* score_b  = (const float*)d_in[15];
  const int*   n_step   = (const int*)d_in[16];
  float* out = (float*)d_out;

  float* fp = (float*)d_ws;
  float* hop_feat = fp; fp += (size_t)NS*HH;
  float* xst  = fp; fp += DI;
  float* hb   = fp; fp += 2*HH;
  float* qwb  = fp; fp += HH;
  float* wb   = fp; fp += NS;
  unsigned short* us = (unsigned short*)fp;
  unsigned short* attn_featH = us; us += (size_t)NS*HH;
  unsigned short* hop_featH  = us; us += (size_t)NS*HH;
  unsigned short* HQTH  = us; us += (size_t)HH*NS;
  unsigned short* HATH  = us; us += (size_t)HH*NS;
  unsigned short* memTH = us; us += (size_t)DI*NS;
  unsigned short* wqTH  = us; us += (size_t)HH*HH;
  unsigned short* wihH  = us; us += (size_t)4*HH*DI;
  unsigned short* whhH  = us; us += (size_t)4*HH*HH;
  int* bar = (int*)(us + 256);
  bar = (int*)(((uintptr_t)bar + 4095) & ~(uintptr_t)4095);
  size_t need = (size_t)((char*)(bar + 8192) - (char*)d_ws);
  if (ws_size < need) return;

  initk<<<8, 1024, 0, stream>>>(bar);
  convk<<<4096, 256, 0, stream>>>(w_ih, wihH, 4*HH*DI);
  convk<<<4096, 256, 0, stream>>>(w_hh, whhH, 4*HH*HH);
  dim3 gg(HH/64, NS/64);
  gemmk<3><<<gg, 256, 0, stream>>>(attn_mem, hop_wm,  hop_feat, hop_featH, NS, HH, DI);
  gemmk<1><<<gg, 256, 0, stream>>>(attn_mem, attn_wm, nullptr, attn_featH, NS, HH, DI);
  gemmk<2><<<gg, 256, 0, stream>>>(hop_feat, hop_wq,  nullptr, HQTH, NS, HH, HH);
  gemmk<2><<<gg, 256, 0, stream>>>(hop_feat, attn_wq, nullptr, HATH, NS, HH, HH);
  transpkH<<<dim3(DI/32, NS/32), dim3(32,8), 0, stream>>>(attn_mem, memTH, NS, DI);
  transpkH<<<dim3(HH/32, HH/32), dim3(32,8), 0, stream>>>(hop_wq, wqTH, HH, HH);

  stepk<<<NB, TPB, 0, stream>>>(attn_featH, hop_featH, HQTH, HATH, memTH, wqTH,
      wihH, whhH, b_ih, b_hh, hop_v, attn_v, init_h, init_c, init_i,
      score_w, score_b, n_step,
      xst, hb, qwb, wb, bar, out);
}

// Round 13
// 7348.635 us; speedup vs baseline: 1.0263x; 1.0263x over previous
//
#include <hip/hip_runtime.h>

#define NS 4096   // sentences
#define DI 1024   // D_IN
#define HH 1024   // HID
#define NB 256    // persistent blocks
#define TPB 1024  // 16 waves/block
#define LOG2E 1.4426950408889634f

// barrier layout (ints): leaf counters at g*1024 (g<8), mid at 8*1024,
// gen copies at (9+k)*1024 (k<8) -> 17*4KB region
#define BAR_INTS (17*1024)

// keep a loaded value alive in VGPRs (not rematerializable)
#define PINU2(v) asm volatile("" : "+v"((v).x), "+v"((v).y))

__device__ __forceinline__ float ld_b(const float* p){
  return __hip_atomic_load(p, __ATOMIC_RELAXED, __HIP_MEMORY_SCOPE_AGENT);
}
__device__ __forceinline__ void st_b(float* p, float v){
  __hip_atomic_store(p, v, __ATOMIC_RELAXED, __HIP_MEMORY_SCOPE_AGENT);
}
__device__ __forceinline__ float fexp2f_(float x){ return __builtin_amdgcn_exp2f(x); }
__device__ __forceinline__ float frcpf_(float x){ return __builtin_amdgcn_rcpf(x); }
__device__ __forceinline__ float ftanh_(float x){ float t=fexp2f_(x*(2.f*LOG2E)); return 1.f-2.f*frcpf_(t+1.f); }
__device__ __forceinline__ float fsigm_(float x){ return frcpf_(1.f+fexp2f_(-x*LOG2E)); }
__device__ __forceinline__ float fexpf_(float x){ return fexp2f_(x*LOG2E); }
__device__ __forceinline__ float bl(unsigned u){ return __uint_as_float(u<<16); }
__device__ __forceinline__ float bh(unsigned u){ return __uint_as_float(u & 0xffff0000u); }
__device__ __forceinline__ unsigned short rne(float f){
  unsigned u = __float_as_uint(f);
  u += 0x7FFFu + ((u>>16)&1u);
  return (unsigned short)(u>>16);
}
__device__ __forceinline__ float red64(float v){
  #pragma unroll
  for (int off=32; off; off>>=1) v += __shfl_xor(v, off, 64);
  return v;
}
// dot of 4 packed bf16 (uint2) with float4
__device__ __forceinline__ float dot4u(uint2 u, float4 x){
  float s = bl(u.x)*x.x;
  s = fmaf(bh(u.x), x.y, s);
  s = fmaf(bl(u.y), x.z, s);
  s = fmaf(bh(u.y), x.w, s);
  return s;
}
__device__ __forceinline__ float att4u(uint2 u, float4 q, float4 v){
  float s = ftanh_(bl(u.x)+q.x)*v.x;
  s = fmaf(ftanh_(bh(u.x)+q.y), v.y, s);
  s = fmaf(ftanh_(bl(u.y)+q.z), v.z, s);
  s = fmaf(ftanh_(bh(u.y)+q.w), v.w, s);
  return s;
}

// ---- tree grid barrier: 8 spread leaf counters + mid counter + 8 gen copies ----
// Proven optimal over 6 variants (r6-r12): last arriver IS the detector;
// serialized-RMW arrival beats store+sweep because protocol latency is NOT
// the floor — skew + LLC communication RTT is.
__device__ __forceinline__ void gbar(int* bar, int ep){
  __syncthreads();
  if (threadIdx.x == 0){
    asm volatile("s_waitcnt vmcnt(0) lgkmcnt(0)" ::: "memory");
    const int bb = blockIdx.x;
    int p1 = __hip_atomic_fetch_add(bar + (bb>>5)*1024, 1, __ATOMIC_RELAXED, __HIP_MEMORY_SCOPE_AGENT);
    if ((p1 & 31) == 31){
      int p2 = __hip_atomic_fetch_add(bar + 8*1024, 1, __ATOMIC_RELAXED, __HIP_MEMORY_SCOPE_AGENT);
      if ((p2 & 7) == 7){
        int g = (p2 >> 3) + 1;
        #pragma unroll
        for (int k=0;k<8;++k)
          __hip_atomic_store(bar + (9+k)*1024, g, __ATOMIC_RELAXED, __HIP_MEMORY_SCOPE_AGENT);
      }
    }
    int* mygen = bar + (9 + (bb&7))*1024;
    while (__hip_atomic_load(mygen, __ATOMIC_RELAXED, __HIP_MEMORY_SCOPE_AGENT) <= ep)
      __builtin_amdgcn_s_sleep(1);
  }
  __syncthreads();
}

// ---------------- precompute kernels ----------------
__global__ void initk(int* bar){ bar[blockIdx.x*1024 + threadIdx.x] = 0; }  // <<<17,1024>>>

template<int MODE>  // 0: fp32 C; 1: bf16 CH; 2: bf16 CH^T; 3: fp32 C + bf16 CH
__global__ __launch_bounds__(256) void gemmk(const float* __restrict__ A,
                                             const float* __restrict__ B,
                                             float* __restrict__ C,
                                             unsigned short* __restrict__ CH,
                                             int M, int N, int K)
{
  __shared__ float As[64][17];
  __shared__ float Bs[16][68];
  const int tid = threadIdx.x;
  const int tx = tid & 15, ty = tid >> 4;
  const int r0 = blockIdx.y*64, c0 = blockIdx.x*64;
  float acc[4][4] = {};
  for (int k0 = 0; k0 < K; k0 += 16){
    int ar = tid >> 2, aq = tid & 3;
    float4 a4 = *(const float4*)&A[(size_t)(r0+ar)*K + k0 + aq*4];
    As[ar][aq*4+0]=a4.x; As[ar][aq*4+1]=a4.y; As[ar][aq*4+2]=a4.z; As[ar][aq*4+3]=a4.w;
    int br = tid >> 4, bq = tid & 15;
    float4 b4 = *(const float4*)&B[(size_t)(k0+br)*N + c0 + bq*4];
    Bs[br][bq*4+0]=b4.x; Bs[br][bq*4+1]=b4.y; Bs[br][bq*4+2]=b4.z; Bs[br][bq*4+3]=b4.w;
    __syncthreads();
    #pragma unroll
    for (int kk=0; kk<16; ++kk){
      float a0=As[ty*4+0][kk], a1=As[ty*4+1][kk], a2=As[ty*4+2][kk], a3=As[ty*4+3][kk];
      float b0=Bs[kk][tx*4+0], b1=Bs[kk][tx*4+1], b2=Bs[kk][tx*4+2], b3=Bs[kk][tx*4+3];
      acc[0][0]+=a0*b0; acc[0][1]+=a0*b1; acc[0][2]+=a0*b2; acc[0][3]+=a0*b3;
      acc[1][0]+=a1*b0; acc[1][1]+=a1*b1; acc[1][2]+=a1*b2; acc[1][3]+=a1*b3;
      acc[2][0]+=a2*b0; acc[2][1]+=a2*b1; acc[2][2]+=a2*b2; acc[2][3]+=a2*b3;
      acc[3][0]+=a3*b0; acc[3][1]+=a3*b1; acc[3][2]+=a3*b2; acc[3][3]+=a3*b3;
    }
    __syncthreads();
  }
  if constexpr (MODE==0 || MODE==3){
    #pragma unroll
    for (int i=0;i<4;++i){
      float4 o; o.x=acc[i][0]; o.y=acc[i][1]; o.z=acc[i][2]; o.w=acc[i][3];
      *(float4*)&C[(size_t)(r0+ty*4+i)*N + c0 + tx*4] = o;
    }
  }
  if constexpr (MODE==1 || MODE==3){
    #pragma unroll
    for (int i=0;i<4;++i){
      ushort4 o; o.x=rne(acc[i][0]); o.y=rne(acc[i][1]); o.z=rne(acc[i][2]); o.w=rne(acc[i][3]);
      *(ushort4*)&CH[(size_t)(r0+ty*4+i)*N + c0 + tx*4] = o;
    }
  }
  if constexpr (MODE==2){
    __shared__ float Cs[64][65];
    #pragma unroll
    for (int i=0;i<4;++i)
      #pragma unroll
      for (int j=0;j<4;++j) Cs[ty*4+i][tx*4+j] = acc[i][j];
    __syncthreads();
    #pragma unroll
    for (int e=0;e<16;++e){
      int idx = tid + 256*e;
      int cc = idx >> 6, rr = idx & 63;
      CH[(size_t)(c0+cc)*M + r0 + rr] = rne(Cs[rr][cc]);
    }
  }
}

__global__ void transpkH(const float* __restrict__ in, unsigned short* __restrict__ out, int R, int C){
  __shared__ float s[32][33];
  int c0 = blockIdx.x*32, r0 = blockIdx.y*32;
  int x = threadIdx.x, y = threadIdx.y;
  for (int i=0;i<32;i+=8) s[y+i][x] = in[(size_t)(r0+y+i)*C + c0 + x];
  __syncthreads();
  for (int i=0;i<32;i+=8) out[(size_t)(c0+y+i)*R + r0 + x] = rne(s[x][y+i]);
}

__global__ void convk(const float* __restrict__ in, unsigned short* __restrict__ out, int n){
  int i = (blockIdx.x*blockDim.x + threadIdx.x)*4;
  if (i < n){
    float4 f = *(const float4*)&in[i];
    ushort4 o; o.x=rne(f.x); o.y=rne(f.y); o.z=rne(f.z); o.w=rne(f.w);
    *(ushort4*)&out[i] = o;
  }
}

// ---------------- persistent step kernel ----------------
// Converged structure (r6/r11 optimum over 12 rounds):
//   registers (33 dwords): feat rows (16), LSTM gate row (16), wq col (1)
//   LDS (96KB): HQ/HA/memT col rows, staged once.
//   8 grid barriers/step (structurally forced all-to-all dependencies);
//   small-vector movement: one coalesced staged pass -> LDS -> consume.
__global__ __launch_bounds__(TPB) void stepk(
  const unsigned short* __restrict__ attn_featH, const unsigned short* __restrict__ hop_featH,
  const unsigned short* __restrict__ HQTH, const unsigned short* __restrict__ HATH,
  const unsigned short* __restrict__ memTH, const unsigned short* __restrict__ wqTH,
  const unsigned short* __restrict__ wihH, const unsigned short* __restrict__ whhH,
  const float* __restrict__ b_ih, const float* __restrict__ b_hh,
  const float* __restrict__ hop_v, const float* __restrict__ attn_v,
  const float* __restrict__ init_h, const float* __restrict__ init_c,
  const float* __restrict__ init_i,
  const float* __restrict__ score_w, const float* __restrict__ score_b,
  const int* __restrict__ n_step,
  float* xst, float* hb, float* qwb, float* wb, int* bar,
  float* __restrict__ out)
{
  const int bb = blockIdx.x, tid = threadIdx.x;
  const int wv = tid>>6, ln = tid&63;
  const int g = wv>>2, sub = wv&3;
  const int rowA = 16*bb + wv;            // att row
  const int R    = g*HH + 4*bb + sub;     // LSTM gate row

  __shared__ unsigned short mls[3][4][4096];  // 96KB: HQ/HA/memT rows for this block's 4 cols
  __shared__ float xh[2*HH];
  __shared__ float qls[HH];
  __shared__ float wls[NS];
  __shared__ float vhop[HH], vatt[HH], swls[HH];
  __shared__ float gbuf[16], pbuf[16], sbuf[16], cl[4];
  int ep = 0;

  // ---- stage col matrices in LDS (once) ----
  #pragma unroll
  for (int gg2=0; gg2<4; ++gg2){
    const size_t r = (size_t)(4*bb+gg2)*NS + tid*4;
    *(ushort4*)&mls[0][gg2][tid*4] = *(const ushort4*)&HQTH [r];
    *(ushort4*)&mls[1][gg2][tid*4] = *(const ushort4*)&HATH [r];
    *(ushort4*)&mls[2][gg2][tid*4] = *(const ushort4*)&memTH[r];
  }

  // ---- pin remaining rows in registers (33 dwords / lane) ----
  uint2 hopf[4], attnf[4], wihr[4], whhr[4], wqr;
  #pragma unroll
  for (int ps=0; ps<4; ++ps){
    const int e0 = ps*256 + ln*4;
    hopf[ps]  = *(const uint2*)&hop_featH [(size_t)rowA*HH + e0];  PINU2(hopf[ps]);
    attnf[ps] = *(const uint2*)&attn_featH[(size_t)rowA*HH + e0];  PINU2(attnf[ps]);
    wihr[ps]  = *(const uint2*)&wihH[(size_t)R*DI + e0];           PINU2(wihr[ps]);
    whhr[ps]  = *(const uint2*)&whhH[(size_t)R*HH + e0];           PINU2(whhr[ps]);
  }
  wqr = *(const uint2*)&wqTH[(size_t)(4*bb+g)*HH + sub*256 + ln*4]; PINU2(wqr);
  const float bR = b_ih[R] + b_hh[R];

  vhop[tid] = hop_v[tid];
  vatt[tid] = attn_v[tid];
  swls[tid] = score_w[tid];
  const int T = *n_step;
  const float sb = score_b[0];
  __syncthreads();

  for (int t=0; t<T; ++t){
    const int hw = (t+1)&1;
    // ---- Ph1: LSTM gates + h update; score[t-1] on block 0 ----
    if (t==0){ xh[tid] = init_i[tid]; xh[HH+tid] = init_h[tid]; }
    else     { xh[tid] = ld_b(&xst[tid]); xh[HH+tid] = ld_b(&hb[(t&1)*HH + tid]); }
    __syncthreads();
    {
      float p = 0.f;
      #pragma unroll
      for (int ps=0; ps<4; ++ps){
        const int e0 = ps*256 + ln*4;
        p += dot4u(wihr[ps], *(const float4*)&xh[e0]);
        p += dot4u(whhr[ps], *(const float4*)&xh[HH+e0]);
      }
      p = red64(p);
      if (ln==0) gbuf[wv] = p + bR;
    }
    __syncthreads();
    if (bb==0 && wv==0 && t>0){
      float a = 0.f;
      #pragma unroll
      for (int ps=0; ps<4; ++ps){
        const int e0 = ps*256 + ln*4;
        float4 x = *(const float4*)&xh[e0], s = *(const float4*)&swls[e0];
        a += x.x*s.x; a = fmaf(x.y,s.y,a); a = fmaf(x.z,s.z,a); a = fmaf(x.w,s.w,a);
      }
      a = red64(a);
      if (ln==0) out[t-1] = a + sb;
    }
    if (tid < 4){
      float ii=fsigm_(gbuf[tid]),   ff=fsigm_(gbuf[4+tid]);
      float gg=ftanh_(gbuf[8+tid]), oo=fsigm_(gbuf[12+tid]);
      float c = (t==0) ? init_c[4*bb+tid] : cl[tid];
      float c2 = ff*c + ii*gg;
      cl[tid] = c2;
      st_b(&hb[(size_t)hw*HH + 4*bb + tid], oo*ftanh_(c2));
    }
    gbar(bar, ep); ++ep;

    // ---- Ph2: qw1 = h @ hop_wq ----
    qls[tid] = ld_b(&hb[(size_t)hw*HH + tid]);
    __syncthreads();
    {
      float a = dot4u(wqr, *(const float4*)&qls[sub*256 + ln*4]);
      a = red64(a);
      if (ln==0) pbuf[wv] = a;
    }
    __syncthreads();
    if (tid < 4)
      st_b(&qwb[4*bb+tid], pbuf[4*tid]+pbuf[4*tid+1]+pbuf[4*tid+2]+pbuf[4*tid+3]);
    gbar(bar, ep); ++ep;

    // ---- 3 hops: att (own row, regs) | col (own 4 dims, LDS matrices) ----
    #pragma unroll
    for (int hop=0; hop<3; ++hop){
      // att: e = sum tanh(F[n]+qw).v -> w=exp(e)
      qls[tid] = ld_b(&qwb[tid]);
      __syncthreads();
      {
        float e = 0.f;
        #pragma unroll
        for (int ps=0; ps<4; ++ps){
          const int e0 = ps*256 + ln*4;
          float4 q = *(const float4*)&qls[e0];
          if (hop<2) e += att4u(hopf[ps],  q, *(const float4*)&vhop[e0]);
          else       e += att4u(attnf[ps], q, *(const float4*)&vatt[e0]);
        }
        e = red64(e);
        if (ln==0) st_b(&wb[rowA], fexpf_(e));   // |e|<=sum|v|: no overflow
      }
      gbar(bar, ep); ++ep;

      // col: stage all 4096 w in LDS; dot with LDS matrix rows; denom = LDS sum
      wls[tid]      = ld_b(&wb[tid]);
      wls[tid+1024] = ld_b(&wb[tid+1024]);
      wls[tid+2048] = ld_b(&wb[tid+2048]);
      wls[tid+3072] = ld_b(&wb[tid+3072]);
      __syncthreads();
      {
        float a = 0.f;
        const unsigned short* mrow = &mls[hop][g][sub*1024];
        #pragma unroll
        for (int ps=0; ps<4; ++ps){
          const int e0 = ps*256 + ln*4;
          float4 w4 = *(const float4*)&wls[sub*1024 + e0];
          uint2 m = *(const uint2*)&mrow[e0];
          a += dot4u(m, w4);
        }
        a = red64(a);
        if (ln==0) pbuf[wv] = a;
        // per-wave chunk sum of w for the softmax denominator (local)
        float4 sv = *(const float4*)&wls[wv*256 + ln*4];
        float s4 = sv.x + sv.y + sv.z + sv.w;
        s4 = red64(s4);
        if (ln==0) sbuf[wv] = s4;
      }
      __syncthreads();
      if (tid < 4){
        float stot = 0.f;
        #pragma unroll
        for (int k=0;k<16;++k) stot += sbuf[k];
        float s = (pbuf[4*tid]+pbuf[4*tid+1]+pbuf[4*tid+2]+pbuf[4*tid+3]) / stot;
        float* dst = (hop==2) ? xst : qwb;
        st_b(&dst[4*bb+tid], s);
      }
      gbar(bar, ep); ++ep;
    }
  }
  // final score for t = T-1
  if (bb==0 && wv==0 && T>0){
    float a = 0.f;
    #pragma unroll
    for (int m=0;m<16;++m){ int i = ln + (m<<6); a = fmaf(ld_b(&xst[i]), swls[i], a); }
    a = red64(a);
    if (ln==0) out[T-1] = a + sb;
  }
}

// ---------------- host launch ----------------
extern "C" void kernel_launch(void* const* d_in, const int* in_sizes, int n_in,
                              void* d_out, int out_size, void* d_ws, size_t ws_size,
                              hipStream_t stream)
{
  (void)in_sizes; (void)n_in; (void)out_size;
  const float* attn_mem = (const float*)d_in[0];
  const float* attn_wm  = (const float*)d_in[1];
  const float* attn_wq  = (const float*)d_in[2];
  const float* attn_v   = (const float*)d_in[3];
  const float* hop_wm   = (const float*)d_in[4];
  const float* hop_wq   = (const float*)d_in[5];
  const float* hop_v    = (const float*)d_in[6];
  const float* init_h   = (const float*)d_in[7];
  const float* init_c   = (const float*)d_in[8];
  const float* init_i   = (const float*)d_in[9];
  const float* w_ih     = (const float*)d_in[10];
  const float* w_hh     = (const float*)d_in[11];
  const float* b_ih     = (const float*)d_in[12];
  const float* b_hh     = (const float*)d_in[13];
  const float* score_w  = (const float*)d_in[14];
  const float* score_b  = (const float*)d_in[15];
  const int*   n_step   = (const int*)d_in[16];
  float* out = (float*)d_out;

  float* fp = (float*)d_ws;
  float* hop_feat = fp; fp += (size_t)NS*HH;
  float* xst  = fp; fp += DI;
  float* hb   = fp; fp += 2*HH;
  float* qwb  = fp; fp += HH;
  float* wb   = fp; fp += NS;
  unsigned short* us = (unsigned short*)fp;
  unsigned short* attn_featH = us; us += (size_t)NS*HH;
  unsigned short* hop_featH  = us; us += (size_t)NS*HH;
  unsigned short* HQTH  = us; us += (size_t)HH*NS;
  unsigned short* HATH  = us; us += (size_t)HH*NS;
  unsigned short* memTH = us; us += (size_t)DI*NS;
  unsigned short* wqTH  = us; us += (size_t)HH*HH;
  unsigned short* wihH  = us; us += (size_t)4*HH*DI;
  unsigned short* whhH  = us; us += (size_t)4*HH*HH;
  int* bar = (int*)(us + 256);
  bar = (int*)(((uintptr_t)bar + 4095) & ~(uintptr_t)4095);
  size_t need = (size_t)((char*)(bar + BAR_INTS) - (char*)d_ws);
  if (ws_size < need) return;

  initk<<<17, 1024, 0, stream>>>(bar);
  convk<<<4096, 256, 0, stream>>>(w_ih, wihH, 4*HH*DI);
  convk<<<4096, 256, 0, stream>>>(w_hh, whhH, 4*HH*HH);
  dim3 gg(HH/64, NS/64);
  gemmk<3><<<gg, 256, 0, stream>>>(attn_mem, hop_wm,  hop_feat, hop_featH, NS, HH, DI);
  gemmk<1><<<gg, 256, 0, stream>>>(attn_mem, attn_wm, nullptr, attn_featH, NS, HH, DI);
  gemmk<2><<<gg, 256, 0, stream>>>(hop_feat, hop_wq,  nullptr, HQTH, NS, HH, HH);
  gemmk<2><<<gg, 256, 0, stream>>>(hop_feat, attn_wq, nullptr, HATH, NS, HH, HH);
  transpkH<<<dim3(DI/32, NS/32), dim3(32,8), 0, stream>>>(attn_mem, memTH, NS, DI);
  transpkH<<<dim3(HH/32, HH/32), dim3(32,8), 0, stream>>>(hop_wq, wqTH, HH, HH);

  stepk<<<NB, TPB, 0, stream>>>(attn_featH, hop_featH, HQTH, HATH, memTH, wqTH,
      wihH, whhH, b_ih, b_hh, hop_v, attn_v, init_h, init_c, init_i,
      score_w, score_b, n_step,
      xst, hb, qwb, wb, bar, out);
}